// Round 6
// baseline (254.544 us; speedup 1.0000x reference)
//
#include <hip/hip_runtime.h>
#include <hip/hip_fp16.h>
#include <cstdint>
#include <cstddef>

#define NN 100000
#define NE 1600000
#define D 128
#define NBK 782            // ceil(NN / 128) buckets of 128 nodes
#define NBLK_P 800         // partition blocks (3.1/CU; was 200 = 0.78/CU, latency-bound)
#define EPB 2000           // edges per partition block (800*2000 = 1.6M exact)
#define CAP 3072           // slots per bucket (mean 2048, +22 sigma; overflow clamped)

typedef _Float16 half8 __attribute__((ext_vector_type(8)));
typedef _Float16 half4v __attribute__((ext_vector_type(4)));
typedef float f32x4 __attribute__((ext_vector_type(4)));

// ---------------- workspace layout (bytes) ----------------
// part  : 782*3072 u32 @ 0         (9,609,216)   } dead after p4_csr; overlapped by h
// gcnt  : 782*16 u32  @ 9,609,216  (   50,048)   } (1 counter/line; memset pre-zeroed)
// h'    : NN*128 f16  @ 0          (25,600,000)  = dinv[row] * (x@W1), written after p4
// z'    : NN*2 f32    @ 25,600,000 (   800,000)  = dinv[row] * (relu(agg+b1)@W2)
// dinv  : NN f32      @ 26,400,000 (   400,000)
// rp    : NN u32      @ 26,800,000 (   400,000)  per-node range start (slotted space)
// re    : NN u32      @ 27,200,000 (   400,000)  per-node range end
// col   : 782*3072 u32 @ 27,600,000 (9,609,216+256 pad)  bucket-slotted
// Wt    : 128*128 f16 @ 37,300,000 (    32,768)  -> total ~37.3 MB (ws = 256 MiB)
// NOTE: agg1's col-window load may read up to col[p0+63] -> stays inside the
// slotted col allocation (+256B pad); unused lanes masked by (k<degc) selects.

// PSCAT: fused histogram + range-reserve + scatter. The LDS histogram exists
// only to batch global reservation atomics (1 per nonempty (block,bucket)),
// so the grid is free to be sized for occupancy — 800 blocks = 3.1/CU.
// Bucket order within a reserved range is arbitrary — p4 rebuilds per-node
// order via atomics anyway. Blocks 0..63 also emit Wt[n][k] = fp16 W1[k][n].
__launch_bounds__(256)
__global__ void pscat_k(const int* __restrict__ ei, unsigned* __restrict__ gcnt,
                        unsigned* __restrict__ part,
                        const float* __restrict__ W, _Float16* __restrict__ Wt) {
    __shared__ unsigned hist[NBK];
    __shared__ unsigned run[NBK];
    int tid = threadIdx.x, b = blockIdx.x;
    for (int k = tid; k < NBK; k += 256) hist[k] = 0u;
    __syncthreads();
    int e0 = b * EPB;
    for (int i = tid * 4; i < EPB; i += 1024) {
        int4 d4 = *(const int4*)(ei + NE + e0 + i);
        atomicAdd(&hist[d4.x >> 7], 1u);
        atomicAdd(&hist[d4.y >> 7], 1u);
        atomicAdd(&hist[d4.z >> 7], 1u);
        atomicAdd(&hist[d4.w >> 7], 1u);
    }
    __syncthreads();
    // reserve [run[k], run[k]+hist[k]) in bucket k via one global atomic each
    for (int k = tid; k < NBK; k += 256) {
        unsigned c = hist[k];
        run[k] = c ? atomicAdd(&gcnt[k * 16], c) : 0u;
    }
    if (b < 64) {  // fused Wt transpose+cast, overlaps the atomic latency
        int idx = b * 256 + tid;
        int n = idx >> 7, kk = idx & 127;
        Wt[idx] = (_Float16)W[kk * 128 + n];
    }
    __syncthreads();
    for (int i = tid * 4; i < EPB; i += 1024) {
        int4 s4 = *(const int4*)(ei + e0 + i);
        int4 d4 = *(const int4*)(ei + NE + e0 + i);
        unsigned k, slot;
        k = (unsigned)(d4.x >> 7); slot = atomicAdd(&run[k], 1u);
        if (slot < CAP) part[(size_t)k * CAP + slot] = (unsigned)s4.x | ((unsigned)(d4.x & 127) << 20);
        k = (unsigned)(d4.y >> 7); slot = atomicAdd(&run[k], 1u);
        if (slot < CAP) part[(size_t)k * CAP + slot] = (unsigned)s4.y | ((unsigned)(d4.y & 127) << 20);
        k = (unsigned)(d4.z >> 7); slot = atomicAdd(&run[k], 1u);
        if (slot < CAP) part[(size_t)k * CAP + slot] = (unsigned)s4.z | ((unsigned)(d4.z & 127) << 20);
        k = (unsigned)(d4.w >> 7); slot = atomicAdd(&run[k], 1u);
        if (slot < CAP) part[(size_t)k * CAP + slot] = (unsigned)s4.w | ((unsigned)(d4.w & 127) << 20);
    }
}

// P4: one block per bucket. Range is bucket-local [k*CAP, k*CAP+cnt) — no
// global scan needed. Count per node in LDS, scan, emit rp/re/dinv, regroup
// slotted part -> per-node-contiguous col (still bucket-slotted space).
__launch_bounds__(256)
__global__ void p4_csr_k(const unsigned* __restrict__ part, const unsigned* __restrict__ gcnt,
                         unsigned* __restrict__ rp, unsigned* __restrict__ re,
                         float* __restrict__ dinv, unsigned* __restrict__ col) {
    __shared__ unsigned c[128], p[128], run[128];
    int tid = threadIdx.x, k = blockIdx.x;
    int n0 = k << 7;
    int nodes = (NN - n0 < 128) ? (NN - n0) : 128;
    unsigned cnt = gcnt[k * 16];
    if (cnt > CAP) cnt = CAP;  // overflow clamp (statistically impossible)
    unsigned e0c = (unsigned)k * CAP;
    const unsigned* pk = part + (size_t)k * CAP;

    if (tid < 128) c[tid] = 0u;
    __syncthreads();
    for (unsigned t = tid; t < cnt; t += 256)
        atomicAdd(&c[(pk[t] >> 20) & 127], 1u);
    __syncthreads();

    unsigned myc = (tid < 128) ? c[tid] : 0u;
    if (tid < 128) p[tid] = myc;
    __syncthreads();
    for (int off = 1; off < 128; off <<= 1) {
        unsigned u = 0;
        if (tid < 128 && tid >= off) u = p[tid - off];
        __syncthreads();
        if (tid < 128) p[tid] += u;
        __syncthreads();
    }
    if (tid < 128) {
        unsigned excl = p[tid] - myc;
        run[tid] = excl;
        if (tid < nodes) {
            rp[n0 + tid] = e0c + excl;
            re[n0 + tid] = e0c + excl + myc;
            dinv[n0 + tid] = rsqrtf((float)(myc + 1u));
        }
    }
    __syncthreads();

    for (unsigned t = tid; t < cnt; t += 256) {
        unsigned v = pk[t];
        unsigned dlo = (v >> 20) & 127;
        unsigned pos = e0c + atomicAdd(&run[dlo], 1u);
        col[pos] = v & 0xFFFFFu;
    }
}

// h' = dinv ⊙ (x @ W1), fp16 out, MFMA 16x16x32 f16. 128 rows/block, 4 waves;
// wave w covers rows w*32..w*32+31 (2 row-tiles) × all 8 col-tiles -> B-frag
// reused across 2 MFMAs. x staged in K-halves of 64 so LDS = 34.8K (wt) +
// 18.4K (xs) = 52K -> 3 blocks/CU; 782 blocks ≈ one co-resident round.
// Verified layouts: A[m=lane&15][k=(lane>>4)*8+j], B[k][n=lane&15],
//                   C/D col=lane&15 row=(lane>>4)*4+reg.
__launch_bounds__(256)
__global__ void gemm1_k(const float* __restrict__ x, const _Float16* __restrict__ Wt,
                        const float* __restrict__ dinv, _Float16* __restrict__ h) {
    __shared__ _Float16 wt[128 * 136];  // B: wt[n][k]; reused as epilogue buffer
    __shared__ _Float16 xs[128 * 72];   // A: xs[row][k within 64-half]
    int tid = threadIdx.x;
    int rb = blockIdx.x * 128;
    int w = tid >> 6, lane = tid & 63;
    int m = lane & 15, q4 = lane >> 4;

    // stage Wt: 2048 half8 chunks, coalesced global, conflict-free LDS
#pragma unroll
    for (int q = 0; q < 8; q++) {
        int idx = q * 256 + tid;
        int n = idx >> 4, k8 = (idx & 15) * 8;
        *(half8*)(&wt[n * 136 + k8]) = *(const half8*)(Wt + n * 128 + k8);
    }

    f32x4 acc[2][8];
#pragma unroll
    for (int rt = 0; rt < 2; rt++)
#pragma unroll
        for (int nt = 0; nt < 8; nt++) acc[rt][nt] = (f32x4){0.f, 0.f, 0.f, 0.f};

    for (int ks = 0; ks <= 64; ks += 64) {
        if (ks) __syncthreads();  // previous xs fully consumed
        // stage x rows [rb, rb+128) cols [ks, ks+64), fp32 -> fp16
#pragma unroll
        for (int q = 0; q < 8; q++) {
            int idx = q * 256 + tid;        // 0..2047
            int row = idx >> 4;
            int c4 = (idx & 15) * 4;
            int gr = rb + row;
            float4 v = (gr < NN) ? *(const float4*)(x + (size_t)gr * 128 + ks + c4)
                                 : make_float4(0, 0, 0, 0);
            half4v hv = { (_Float16)v.x, (_Float16)v.y, (_Float16)v.z, (_Float16)v.w };
            *(half4v*)(&xs[row * 72 + c4]) = hv;
        }
        __syncthreads();

#pragma unroll
        for (int kc = 0; kc < 2; kc++) {
            half8 a0 = *(const half8*)(&xs[(w * 32 + m) * 72 + kc * 32 + q4 * 8]);
            half8 a1 = *(const half8*)(&xs[(w * 32 + 16 + m) * 72 + kc * 32 + q4 * 8]);
#pragma unroll
            for (int nt = 0; nt < 8; nt++) {
                half8 bf = *(const half8*)(&wt[(nt * 16 + m) * 136 + ks + kc * 32 + q4 * 8]);
                acc[0][nt] = __builtin_amdgcn_mfma_f32_16x16x32_f16(a0, bf, acc[0][nt], 0, 0, 0);
                acc[1][nt] = __builtin_amdgcn_mfma_f32_16x16x32_f16(a1, bf, acc[1][nt], 0, 0, 0);
            }
        }
    }

    // epilogue: scale by dinv[row], fp16, stage in wt (dead), coalesced store
    float dv[2][4];
#pragma unroll
    for (int rt = 0; rt < 2; rt++)
#pragma unroll
        for (int r = 0; r < 4; r++) {
            int ri = rb + w * 32 + rt * 16 + q4 * 4 + r;
            dv[rt][r] = (ri < NN) ? dinv[ri] : 0.f;
        }
    __syncthreads();  // all wt reads done
#pragma unroll
    for (int rt = 0; rt < 2; rt++)
#pragma unroll
        for (int nt = 0; nt < 8; nt++)
#pragma unroll
            for (int r = 0; r < 4; r++)
                wt[(w * 32 + rt * 16 + q4 * 4 + r) * 136 + nt * 16 + m] =
                    (_Float16)(acc[rt][nt][r] * dv[rt][r]);
    __syncthreads();
#pragma unroll
    for (int q = 0; q < 8; q++) {
        int idx = q * 256 + tid;
        int row = idx >> 4;
        int c8 = (idx & 15) * 8;
        int gr = rb + row;
        if (gr < NN)
            *(half8*)(h + (size_t)gr * 128 + c8) = *(const half8*)(&wt[row * 136 + c8]);
    }
}

// Layer-1 aggregation of prescaled h' + bias/ReLU + 128x2 W2 projection.
// One wave per node; lane holds half2 (4B chunk; 64 lanes = full 256B row).
// Measured at the fill-path roofline (58.9 us vs 193MB/3.37TB/s = 57 us):
// col window loaded once (col[p0+lane]), row ids via readlane -> SGPR gather
// addresses, no degree tails: full 16-gather rounds, padding slots gather
// row i (hot), corrected exactly by f = 1 + deg - 16*ceil(deg/16).
__launch_bounds__(256)
__global__ void agg1_k(const _Float16* __restrict__ h, const unsigned* __restrict__ rp,
                       const unsigned* __restrict__ re, const unsigned* __restrict__ col,
                       const float* __restrict__ dinv, const float* __restrict__ b1,
                       const float* __restrict__ W2, float* __restrict__ z) {
    int i = (blockIdx.x * 256 + threadIdx.x) >> 6;
    int lane = threadIdx.x & 63;
    if (i >= NN) return;
    unsigned si = __builtin_amdgcn_readfirstlane((unsigned)i);  // force SGPR

    const __half2* hb = (const __half2*)h;
    unsigned p0 = __builtin_amdgcn_readfirstlane(rp[si]);
    unsigned p1 = __builtin_amdgcn_readfirstlane(re[si]);
    int deg = (int)(p1 - p0);

    // col window: one per-lane load covers up to 64 edge ids. May read past p1
    // (stays inside the padded slotted col); unused lanes masked by (k<degc).
    unsigned cv = col[p0 + (unsigned)lane];

    int degc = deg > 64 ? 64 : deg;
    int R = (degc + 15) >> 4;                 // full 16-rounds incl. padding
    float2 sv = __half22float2(hb[(size_t)si * 64u + lane]);
    float f = (float)(1 + degc - 16 * R);     // corrects padding reads of row si
    float ax = f * sv.x, ay = f * sv.y;

#define ROUND16(r)                                                           \
    {                                                                        \
        float2 vv[16];                                                       \
        _Pragma("unroll")                                                    \
        for (int t = 0; t < 16; t++) {                                       \
            int k = (r) * 16 + t;                                            \
            unsigned s = (k < degc) ? __builtin_amdgcn_readlane(cv, k) : si; \
            vv[t] = __half22float2(hb[(size_t)s * 64u + lane]);              \
        }                                                                    \
        ax += ((vv[0].x + vv[1].x) + (vv[2].x + vv[3].x))                    \
            + ((vv[4].x + vv[5].x) + (vv[6].x + vv[7].x))                    \
            + ((vv[8].x + vv[9].x) + (vv[10].x + vv[11].x))                  \
            + ((vv[12].x + vv[13].x) + (vv[14].x + vv[15].x));               \
        ay += ((vv[0].y + vv[1].y) + (vv[2].y + vv[3].y))                    \
            + ((vv[4].y + vv[5].y) + (vv[6].y + vv[7].y))                    \
            + ((vv[8].y + vv[9].y) + (vv[10].y + vv[11].y))                  \
            + ((vv[12].y + vv[13].y) + (vv[14].y + vv[15].y));               \
    }

    if (degc > 0)  ROUND16(0)
    if (degc > 16) ROUND16(1)
    if (degc > 32) ROUND16(2)
    if (degc > 48) ROUND16(3)
#undef ROUND16

    // deg > 64 remainder (Poisson(16): essentially never taken)
    for (unsigned e = p0 + 64; e < p1; ++e) {
        unsigned s_ = __builtin_amdgcn_readfirstlane(col[e]);
        float2 v = __half22float2(hb[(size_t)s_ * 64u + lane]);
        ax += v.x;
        ay += v.y;
    }

    float di = dinv[si];
    ax *= di;
    ay *= di;

    float2 bv = ((const float2*)b1)[lane];
    float h0 = fmaxf(ax + bv.x, 0.f);
    float h1 = fmaxf(ay + bv.y, 0.f);

    float4 w = ((const float4*)W2)[lane];
    float pz0 = fmaf(h0, w.x, h1 * w.z);
    float pz1 = fmaf(h0, w.y, h1 * w.w);
#pragma unroll
    for (int off = 32; off > 0; off >>= 1) {
        pz0 += __shfl_down(pz0, off);
        pz1 += __shfl_down(pz1, off);
    }
    if (lane == 0) {
        float2* zp = (float2*)(z + (size_t)si * 2);
        *zp = make_float2(pz0 * di, pz1 * di);  // prescale for layer-2 aggregation
    }
}

// Layer-2 aggregation over prescaled z'. 16 lanes per node (avg degree 16):
// 4 nodes/wave, width-16 shuffle reduce. out[i] = (Σ z'[s] + z'[i])*dinv[i] + b2.
__launch_bounds__(256)
__global__ void agg2_k(const float* __restrict__ z, const unsigned* __restrict__ rp,
                       const unsigned* __restrict__ re, const unsigned* __restrict__ col,
                       const float* __restrict__ dinv, const float* __restrict__ b2,
                       float* __restrict__ out) {
    int i = (blockIdx.x * 256 + threadIdx.x) >> 4;
    int sl = threadIdx.x & 15;
    if (i >= NN) return;

    unsigned p0 = rp[i], p1 = re[i];
    float a0 = 0.f, a1 = 0.f;
    for (unsigned e = p0 + sl; e < p1; e += 16) {
        unsigned s = col[e];
        float2 v = ((const float2*)z)[s];
        a0 += v.x;
        a1 += v.y;
    }
#pragma unroll
    for (int off = 8; off > 0; off >>= 1) {
        a0 += __shfl_down(a0, off, 16);
        a1 += __shfl_down(a1, off, 16);
    }
    if (sl == 0) {
        float di = dinv[i];
        float2 zi = ((const float2*)z)[i];
        out[(size_t)i * 2]     = (a0 + zi.x) * di + b2[0];
        out[(size_t)i * 2 + 1] = (a1 + zi.y) * di + b2[1];
    }
}

extern "C" void kernel_launch(void* const* d_in, const int* in_sizes, int n_in,
                              void* d_out, int out_size, void* d_ws, size_t ws_size,
                              hipStream_t stream) {
    const float* x  = (const float*)d_in[0];
    const int*   ei = (const int*)d_in[1];
    const float* W1 = (const float*)d_in[2];
    const float* b1 = (const float*)d_in[3];
    const float* W2 = (const float*)d_in[4];
    const float* b2 = (const float*)d_in[5];
    float* out = (float*)d_out;

    char* ws = (char*)d_ws;
    unsigned* part = (unsigned*)(ws);               // slotted buckets, dead before gemm1
    unsigned* gcnt = (unsigned*)(ws + 9609216);     // padded counters (1/line)
    _Float16* h    = (_Float16*)(ws);
    float*    z    = (float*)(ws + 25600000);
    float*    dinv = (float*)(ws + 26400000);
    unsigned* rp   = (unsigned*)(ws + 26800000);
    unsigned* re   = (unsigned*)(ws + 27200000);
    unsigned* col  = (unsigned*)(ws + 27600000);
    _Float16* Wt   = (_Float16*)(ws + 37300000);

    hipMemsetAsync(gcnt, 0, 782 * 16 * sizeof(unsigned), stream);
    pscat_k<<<NBLK_P, 256, 0, stream>>>(ei, gcnt, part, W1, Wt);
    p4_csr_k<<<NBK, 256, 0, stream>>>(part, gcnt, rp, re, dinv, col);

    gemm1_k<<<(NN + 127) / 128, 256, 0, stream>>>(x, Wt, dinv, h);
    agg1_k<<<(NN * 64 + 255) / 256, 256, 0, stream>>>(h, rp, re, col, dinv, b1, W2, z);
    agg2_k<<<(NN * 16 + 255) / 256, 256, 0, stream>>>(z, rp, re, col, dinv, b2, out);
}

// Round 7
// 225.025 us; speedup vs baseline: 1.1312x; 1.1312x over previous
//
#include <hip/hip_runtime.h>
#include <hip/hip_fp16.h>
#include <cstdint>
#include <cstddef>

#define NN 100000
#define NE 1600000
#define D 128
#define NBK 782            // ceil(NN / 128) buckets of 128 nodes
#define NBLK_P 250         // partition blocks (1024 thr: 4000 waves = 16/CU)
#define EPB 6400           // edges per partition block (250*6400 = 1.6M exact)
#define CAP 3072           // slots per bucket (mean 2048, +22 sigma; overflow clamped)

typedef _Float16 half8 __attribute__((ext_vector_type(8)));
typedef _Float16 half4v __attribute__((ext_vector_type(4)));
typedef float f32x4 __attribute__((ext_vector_type(4)));

// ---------------- workspace layout (bytes) ----------------
// part  : 782*3072 u32 @ 0         (9,609,216)   } dead after p4_csr; overlapped by h
// gcnt  : 782*16 u32  @ 9,609,216  (   50,048)   } (1 counter/line; memset pre-zeroed)
// h'    : NN*128 f16  @ 0          (25,600,000)  = dinv[row] * (x@W1), written after p4
// z'    : NN*2 f32    @ 25,600,000 (   800,000)  = dinv[row] * (relu(agg+b1)@W2)
// dinv  : NN f32      @ 26,400,000 (   400,000)
// rp    : NN u32      @ 26,800,000 (   400,000)  per-node range start (slotted space)
// re    : NN u32      @ 27,200,000 (   400,000)  per-node range end
// col   : 782*3072 u32 @ 27,600,000 (9,609,216+256 pad)  bucket-slotted
// Wt    : 128*128 f16 @ 37,300,000 (    32,768)  -> total ~37.3 MB (ws = 256 MiB)
// NOTE: agg1's col-window load may read up to col[p0+63] -> stays inside the
// slotted col allocation (+256B pad); unused lanes masked by (k<degc) selects.

// PSCAT: fused histogram + range-reserve + scatter. Occupancy tuning history:
// 200x256 = 0.8 wave/SIMD, latency-bound (~27us); 800x256 shortened per-
// (block,bucket) runs 10.2->2.6 slots -> 8x write amplification, 60us (R6).
// 250x1024 keeps run length 8.2 (write amp ~R5 level) with 5x the waves.
__launch_bounds__(1024)
__global__ void pscat_k(const int* __restrict__ ei, unsigned* __restrict__ gcnt,
                        unsigned* __restrict__ part,
                        const float* __restrict__ W, _Float16* __restrict__ Wt) {
    __shared__ unsigned hist[NBK];
    __shared__ unsigned run[NBK];
    int tid = threadIdx.x, b = blockIdx.x;
    for (int k = tid; k < NBK; k += 1024) hist[k] = 0u;
    __syncthreads();
    int e0 = b * EPB;
    for (int i = tid * 4; i < EPB; i += 4096) {
        int4 d4 = *(const int4*)(ei + NE + e0 + i);
        atomicAdd(&hist[d4.x >> 7], 1u);
        atomicAdd(&hist[d4.y >> 7], 1u);
        atomicAdd(&hist[d4.z >> 7], 1u);
        atomicAdd(&hist[d4.w >> 7], 1u);
    }
    __syncthreads();
    // reserve [run[k], run[k]+hist[k]) in bucket k via one global atomic each
    for (int k = tid; k < NBK; k += 1024) {
        unsigned c = hist[k];
        run[k] = c ? atomicAdd(&gcnt[k * 16], c) : 0u;
    }
    if (b < 16) {  // fused Wt transpose+cast (16384 elems over 16 blocks)
        int idx = b * 1024 + tid;
        int n = idx >> 7, kk = idx & 127;
        Wt[idx] = (_Float16)W[kk * 128 + n];
    }
    __syncthreads();
    for (int i = tid * 4; i < EPB; i += 4096) {
        int4 s4 = *(const int4*)(ei + e0 + i);
        int4 d4 = *(const int4*)(ei + NE + e0 + i);
        unsigned k, slot;
        k = (unsigned)(d4.x >> 7); slot = atomicAdd(&run[k], 1u);
        if (slot < CAP) part[(size_t)k * CAP + slot] = (unsigned)s4.x | ((unsigned)(d4.x & 127) << 20);
        k = (unsigned)(d4.y >> 7); slot = atomicAdd(&run[k], 1u);
        if (slot < CAP) part[(size_t)k * CAP + slot] = (unsigned)s4.y | ((unsigned)(d4.y & 127) << 20);
        k = (unsigned)(d4.z >> 7); slot = atomicAdd(&run[k], 1u);
        if (slot < CAP) part[(size_t)k * CAP + slot] = (unsigned)s4.z | ((unsigned)(d4.z & 127) << 20);
        k = (unsigned)(d4.w >> 7); slot = atomicAdd(&run[k], 1u);
        if (slot < CAP) part[(size_t)k * CAP + slot] = (unsigned)s4.w | ((unsigned)(d4.w & 127) << 20);
    }
}

// P4: one block per bucket. Range is bucket-local [k*CAP, k*CAP+cnt) — no
// global scan needed. Count per node in LDS, scan, emit rp/re/dinv, regroup
// slotted part -> per-node-contiguous col (still bucket-slotted space).
__launch_bounds__(256)
__global__ void p4_csr_k(const unsigned* __restrict__ part, const unsigned* __restrict__ gcnt,
                         unsigned* __restrict__ rp, unsigned* __restrict__ re,
                         float* __restrict__ dinv, unsigned* __restrict__ col) {
    __shared__ unsigned c[128], p[128], run[128];
    int tid = threadIdx.x, k = blockIdx.x;
    int n0 = k << 7;
    int nodes = (NN - n0 < 128) ? (NN - n0) : 128;
    unsigned cnt = gcnt[k * 16];
    if (cnt > CAP) cnt = CAP;  // overflow clamp (statistically impossible)
    unsigned e0c = (unsigned)k * CAP;
    const unsigned* pk = part + (size_t)k * CAP;

    if (tid < 128) c[tid] = 0u;
    __syncthreads();
    for (unsigned t = tid; t < cnt; t += 256)
        atomicAdd(&c[(pk[t] >> 20) & 127], 1u);
    __syncthreads();

    unsigned myc = (tid < 128) ? c[tid] : 0u;
    if (tid < 128) p[tid] = myc;
    __syncthreads();
    for (int off = 1; off < 128; off <<= 1) {
        unsigned u = 0;
        if (tid < 128 && tid >= off) u = p[tid - off];
        __syncthreads();
        if (tid < 128) p[tid] += u;
        __syncthreads();
    }
    if (tid < 128) {
        unsigned excl = p[tid] - myc;
        run[tid] = excl;
        if (tid < nodes) {
            rp[n0 + tid] = e0c + excl;
            re[n0 + tid] = e0c + excl + myc;
            dinv[n0 + tid] = rsqrtf((float)(myc + 1u));
        }
    }
    __syncthreads();

    for (unsigned t = tid; t < cnt; t += 256) {
        unsigned v = pk[t];
        unsigned dlo = (v >> 20) & 127;
        unsigned pos = e0c + atomicAdd(&run[dlo], 1u);
        col[pos] = v & 0xFFFFFu;
    }
}

// h' = dinv ⊙ (x @ W1), fp16 out, MFMA 16x16x32 f16. 128 rows/block, 4 waves;
// wave w covers rows w*32..w*32+31 (2 row-tiles) × all 8 col-tiles -> B-frag
// reused across 2 MFMAs. x staged in K-halves of 64 so LDS = 34.8K (wt) +
// 18.4K (xs) = 52K -> 3 blocks/CU; 782 blocks ≈ one co-resident round.
// Verified layouts: A[m=lane&15][k=(lane>>4)*8+j], B[k][n=lane&15],
//                   C/D col=lane&15 row=(lane>>4)*4+reg.
__launch_bounds__(256)
__global__ void gemm1_k(const float* __restrict__ x, const _Float16* __restrict__ Wt,
                        const float* __restrict__ dinv, _Float16* __restrict__ h) {
    __shared__ _Float16 wt[128 * 136];  // B: wt[n][k]; reused as epilogue buffer
    __shared__ _Float16 xs[128 * 72];   // A: xs[row][k within 64-half]
    int tid = threadIdx.x;
    int rb = blockIdx.x * 128;
    int w = tid >> 6, lane = tid & 63;
    int m = lane & 15, q4 = lane >> 4;

    // stage Wt: 2048 half8 chunks, coalesced global, conflict-free LDS
#pragma unroll
    for (int q = 0; q < 8; q++) {
        int idx = q * 256 + tid;
        int n = idx >> 4, k8 = (idx & 15) * 8;
        *(half8*)(&wt[n * 136 + k8]) = *(const half8*)(Wt + n * 128 + k8);
    }

    f32x4 acc[2][8];
#pragma unroll
    for (int rt = 0; rt < 2; rt++)
#pragma unroll
        for (int nt = 0; nt < 8; nt++) acc[rt][nt] = (f32x4){0.f, 0.f, 0.f, 0.f};

    for (int ks = 0; ks <= 64; ks += 64) {
        if (ks) __syncthreads();  // previous xs fully consumed
        // stage x rows [rb, rb+128) cols [ks, ks+64), fp32 -> fp16
#pragma unroll
        for (int q = 0; q < 8; q++) {
            int idx = q * 256 + tid;        // 0..2047
            int row = idx >> 4;
            int c4 = (idx & 15) * 4;
            int gr = rb + row;
            float4 v = (gr < NN) ? *(const float4*)(x + (size_t)gr * 128 + ks + c4)
                                 : make_float4(0, 0, 0, 0);
            half4v hv = { (_Float16)v.x, (_Float16)v.y, (_Float16)v.z, (_Float16)v.w };
            *(half4v*)(&xs[row * 72 + c4]) = hv;
        }
        __syncthreads();

#pragma unroll
        for (int kc = 0; kc < 2; kc++) {
            half8 a0 = *(const half8*)(&xs[(w * 32 + m) * 72 + kc * 32 + q4 * 8]);
            half8 a1 = *(const half8*)(&xs[(w * 32 + 16 + m) * 72 + kc * 32 + q4 * 8]);
#pragma unroll
            for (int nt = 0; nt < 8; nt++) {
                half8 bf = *(const half8*)(&wt[(nt * 16 + m) * 136 + ks + kc * 32 + q4 * 8]);
                acc[0][nt] = __builtin_amdgcn_mfma_f32_16x16x32_f16(a0, bf, acc[0][nt], 0, 0, 0);
                acc[1][nt] = __builtin_amdgcn_mfma_f32_16x16x32_f16(a1, bf, acc[1][nt], 0, 0, 0);
            }
        }
    }

    // epilogue: scale by dinv[row], fp16, stage in wt (dead), coalesced store
    float dv[2][4];
#pragma unroll
    for (int rt = 0; rt < 2; rt++)
#pragma unroll
        for (int r = 0; r < 4; r++) {
            int ri = rb + w * 32 + rt * 16 + q4 * 4 + r;
            dv[rt][r] = (ri < NN) ? dinv[ri] : 0.f;
        }
    __syncthreads();  // all wt reads done
#pragma unroll
    for (int rt = 0; rt < 2; rt++)
#pragma unroll
        for (int nt = 0; nt < 8; nt++)
#pragma unroll
            for (int r = 0; r < 4; r++)
                wt[(w * 32 + rt * 16 + q4 * 4 + r) * 136 + nt * 16 + m] =
                    (_Float16)(acc[rt][nt][r] * dv[rt][r]);
    __syncthreads();
#pragma unroll
    for (int q = 0; q < 8; q++) {
        int idx = q * 256 + tid;
        int row = idx >> 4;
        int c8 = (idx & 15) * 8;
        int gr = rb + row;
        if (gr < NN)
            *(half8*)(h + (size_t)gr * 128 + c8) = *(const half8*)(&wt[row * 136 + c8]);
    }
}

// Layer-1 aggregation of prescaled h' + bias/ReLU + 128x2 W2 projection.
// One wave per node; lane holds half2 (4B chunk; 64 lanes = full 256B row).
// Measured at the fill-path roofline (58.9 us vs 193MB/3.37TB/s = 57 us):
// col window loaded once (col[p0+lane]), row ids via readlane -> SGPR gather
// addresses, no degree tails: full 16-gather rounds, padding slots gather
// row i (hot), corrected exactly by f = 1 + deg - 16*ceil(deg/16).
__launch_bounds__(256)
__global__ void agg1_k(const _Float16* __restrict__ h, const unsigned* __restrict__ rp,
                       const unsigned* __restrict__ re, const unsigned* __restrict__ col,
                       const float* __restrict__ dinv, const float* __restrict__ b1,
                       const float* __restrict__ W2, float* __restrict__ z) {
    int i = (blockIdx.x * 256 + threadIdx.x) >> 6;
    int lane = threadIdx.x & 63;
    if (i >= NN) return;
    unsigned si = __builtin_amdgcn_readfirstlane((unsigned)i);  // force SGPR

    const __half2* hb = (const __half2*)h;
    unsigned p0 = __builtin_amdgcn_readfirstlane(rp[si]);
    unsigned p1 = __builtin_amdgcn_readfirstlane(re[si]);
    int deg = (int)(p1 - p0);

    // col window: one per-lane load covers up to 64 edge ids. May read past p1
    // (stays inside the padded slotted col); unused lanes masked by (k<degc).
    unsigned cv = col[p0 + (unsigned)lane];

    int degc = deg > 64 ? 64 : deg;
    int R = (degc + 15) >> 4;                 // full 16-rounds incl. padding
    float2 sv = __half22float2(hb[(size_t)si * 64u + lane]);
    float f = (float)(1 + degc - 16 * R);     // corrects padding reads of row si
    float ax = f * sv.x, ay = f * sv.y;

#define ROUND16(r)                                                           \
    {                                                                        \
        float2 vv[16];                                                       \
        _Pragma("unroll")                                                    \
        for (int t = 0; t < 16; t++) {                                       \
            int k = (r) * 16 + t;                                            \
            unsigned s = (k < degc) ? __builtin_amdgcn_readlane(cv, k) : si; \
            vv[t] = __half22float2(hb[(size_t)s * 64u + lane]);              \
        }                                                                    \
        ax += ((vv[0].x + vv[1].x) + (vv[2].x + vv[3].x))                    \
            + ((vv[4].x + vv[5].x) + (vv[6].x + vv[7].x))                    \
            + ((vv[8].x + vv[9].x) + (vv[10].x + vv[11].x))                  \
            + ((vv[12].x + vv[13].x) + (vv[14].x + vv[15].x));               \
        ay += ((vv[0].y + vv[1].y) + (vv[2].y + vv[3].y))                    \
            + ((vv[4].y + vv[5].y) + (vv[6].y + vv[7].y))                    \
            + ((vv[8].y + vv[9].y) + (vv[10].y + vv[11].y))                  \
            + ((vv[12].y + vv[13].y) + (vv[14].y + vv[15].y));               \
    }

    if (degc > 0)  ROUND16(0)
    if (degc > 16) ROUND16(1)
    if (degc > 32) ROUND16(2)
    if (degc > 48) ROUND16(3)
#undef ROUND16

    // deg > 64 remainder (Poisson(16): essentially never taken)
    for (unsigned e = p0 + 64; e < p1; ++e) {
        unsigned s_ = __builtin_amdgcn_readfirstlane(col[e]);
        float2 v = __half22float2(hb[(size_t)s_ * 64u + lane]);
        ax += v.x;
        ay += v.y;
    }

    float di = dinv[si];
    ax *= di;
    ay *= di;

    float2 bv = ((const float2*)b1)[lane];
    float h0 = fmaxf(ax + bv.x, 0.f);
    float h1 = fmaxf(ay + bv.y, 0.f);

    float4 w = ((const float4*)W2)[lane];
    float pz0 = fmaf(h0, w.x, h1 * w.z);
    float pz1 = fmaf(h0, w.y, h1 * w.w);
#pragma unroll
    for (int off = 32; off > 0; off >>= 1) {
        pz0 += __shfl_down(pz0, off);
        pz1 += __shfl_down(pz1, off);
    }
    if (lane == 0) {
        float2* zp = (float2*)(z + (size_t)si * 2);
        *zp = make_float2(pz0 * di, pz1 * di);  // prescale for layer-2 aggregation
    }
}

// Layer-2 aggregation over prescaled z'. 16 lanes per node (avg degree 16):
// 4 nodes/wave, width-16 shuffle reduce. out[i] = (Σ z'[s] + z'[i])*dinv[i] + b2.
__launch_bounds__(256)
__global__ void agg2_k(const float* __restrict__ z, const unsigned* __restrict__ rp,
                       const unsigned* __restrict__ re, const unsigned* __restrict__ col,
                       const float* __restrict__ dinv, const float* __restrict__ b2,
                       float* __restrict__ out) {
    int i = (blockIdx.x * 256 + threadIdx.x) >> 4;
    int sl = threadIdx.x & 15;
    if (i >= NN) return;

    unsigned p0 = rp[i], p1 = re[i];
    float a0 = 0.f, a1 = 0.f;
    for (unsigned e = p0 + sl; e < p1; e += 16) {
        unsigned s = col[e];
        float2 v = ((const float2*)z)[s];
        a0 += v.x;
        a1 += v.y;
    }
#pragma unroll
    for (int off = 8; off > 0; off >>= 1) {
        a0 += __shfl_down(a0, off, 16);
        a1 += __shfl_down(a1, off, 16);
    }
    if (sl == 0) {
        float di = dinv[i];
        float2 zi = ((const float2*)z)[i];
        out[(size_t)i * 2]     = (a0 + zi.x) * di + b2[0];
        out[(size_t)i * 2 + 1] = (a1 + zi.y) * di + b2[1];
    }
}

extern "C" void kernel_launch(void* const* d_in, const int* in_sizes, int n_in,
                              void* d_out, int out_size, void* d_ws, size_t ws_size,
                              hipStream_t stream) {
    const float* x  = (const float*)d_in[0];
    const int*   ei = (const int*)d_in[1];
    const float* W1 = (const float*)d_in[2];
    const float* b1 = (const float*)d_in[3];
    const float* W2 = (const float*)d_in[4];
    const float* b2 = (const float*)d_in[5];
    float* out = (float*)d_out;

    char* ws = (char*)d_ws;
    unsigned* part = (unsigned*)(ws);               // slotted buckets, dead before gemm1
    unsigned* gcnt = (unsigned*)(ws + 9609216);     // padded counters (1/line)
    _Float16* h    = (_Float16*)(ws);
    float*    z    = (float*)(ws + 25600000);
    float*    dinv = (float*)(ws + 26400000);
    unsigned* rp   = (unsigned*)(ws + 26800000);
    unsigned* re   = (unsigned*)(ws + 27200000);
    unsigned* col  = (unsigned*)(ws + 27600000);
    _Float16* Wt   = (_Float16*)(ws + 37300000);

    hipMemsetAsync(gcnt, 0, 782 * 16 * sizeof(unsigned), stream);
    pscat_k<<<NBLK_P, 1024, 0, stream>>>(ei, gcnt, part, W1, Wt);
    p4_csr_k<<<NBK, 256, 0, stream>>>(part, gcnt, rp, re, dinv, col);

    gemm1_k<<<(NN + 127) / 128, 256, 0, stream>>>(x, Wt, dinv, h);
    agg1_k<<<(NN * 64 + 255) / 256, 256, 0, stream>>>(h, rp, re, col, dinv, b1, W2, z);
    agg2_k<<<(NN * 16 + 255) / 256, 256, 0, stream>>>(z, rp, re, col, dinv, b2, out);
}

// Round 9
// 219.600 us; speedup vs baseline: 1.1591x; 1.0247x over previous
//
#include <hip/hip_runtime.h>
#include <hip/hip_fp16.h>
#include <cstdint>
#include <cstddef>

#define NN 100000
#define NE 1600000
#define D 128
#define NBK 782            // ceil(NN / 128) buckets of 128 nodes
#define NBLK_P 200         // partition blocks (known-best config, R5)
#define EPB 8000           // edges per partition block (200*8000 = 1.6M exact)
#define CAP 3072           // slots per bucket (mean 2048, +22 sigma; overflow clamped)

typedef _Float16 half8 __attribute__((ext_vector_type(8)));
typedef _Float16 half4v __attribute__((ext_vector_type(4)));
typedef float f32x4 __attribute__((ext_vector_type(4)));

// ---------------- workspace layout (bytes) ----------------
// part  : 782*3072 u32 @ 0         (9,609,216)   read by p4g — h must NOT overlap
//         (R8 crash: fused p4g writes h while other blocks still read part;
//          the old part/h overlap was only safe across a kernel boundary)
// gcnt  : 782*16 u32  @ 9,609,216  (   50,048)   (1 counter/line; memset pre-zeroed)
// z'    : NN*2 f32    @ 25,600,000 (   800,000)  = dinv[row] * (relu(agg+b1)@W2)
// dinv  : NN f32      @ 26,400,000 (   400,000)
// rp    : NN u32      @ 26,800,000 (   400,000)  per-node range start (slotted space)
// re    : NN u32      @ 27,200,000 (   400,000)  per-node range end
// col   : 782*3072 u32 @ 27,600,000 (9,609,216+256 pad)  bucket-slotted
// Wt    : 128*128 f16 @ 37,300,000 (    32,768)
// h'    : NN*128 f16  @ 40,000,000 (25,600,000)  own region -> total 65.6MB (ws 256MiB)
// NOTE: agg1's col-window load may read up to col[p0+63] -> stays inside the
// slotted col allocation (+256B pad); unused lanes masked by (k<degc) selects.

// PSCAT: fused histogram + range-reserve + scatter. 200x256 is the measured
// best (R5=221us); 800x256 fragmented runs -> 8x write amp (R6); 250x1024
// no better (R7). Blocks 0..63 also emit Wt[n][k] = fp16 W1[k][n].
__launch_bounds__(256)
__global__ void pscat_k(const int* __restrict__ ei, unsigned* __restrict__ gcnt,
                        unsigned* __restrict__ part,
                        const float* __restrict__ W, _Float16* __restrict__ Wt) {
    __shared__ unsigned hist[NBK];
    __shared__ unsigned run[NBK];
    int tid = threadIdx.x, b = blockIdx.x;
    for (int k = tid; k < NBK; k += 256) hist[k] = 0u;
    __syncthreads();
    int e0 = b * EPB;
    for (int i = tid * 4; i < EPB; i += 1024) {
        int4 d4 = *(const int4*)(ei + NE + e0 + i);
        atomicAdd(&hist[d4.x >> 7], 1u);
        atomicAdd(&hist[d4.y >> 7], 1u);
        atomicAdd(&hist[d4.z >> 7], 1u);
        atomicAdd(&hist[d4.w >> 7], 1u);
    }
    __syncthreads();
    // reserve [run[k], run[k]+hist[k]) in bucket k via one global atomic each
    for (int k = tid; k < NBK; k += 256) {
        unsigned c = hist[k];
        run[k] = c ? atomicAdd(&gcnt[k * 16], c) : 0u;
    }
    if (b < 64) {  // fused Wt transpose+cast, overlaps the atomic latency
        int idx = b * 256 + tid;
        int n = idx >> 7, kk = idx & 127;
        Wt[idx] = (_Float16)W[kk * 128 + n];
    }
    __syncthreads();
    for (int i = tid * 4; i < EPB; i += 1024) {
        int4 s4 = *(const int4*)(ei + e0 + i);
        int4 d4 = *(const int4*)(ei + NE + e0 + i);
        unsigned k, slot;
        k = (unsigned)(d4.x >> 7); slot = atomicAdd(&run[k], 1u);
        if (slot < CAP) part[(size_t)k * CAP + slot] = (unsigned)s4.x | ((unsigned)(d4.x & 127) << 20);
        k = (unsigned)(d4.y >> 7); slot = atomicAdd(&run[k], 1u);
        if (slot < CAP) part[(size_t)k * CAP + slot] = (unsigned)s4.y | ((unsigned)(d4.y & 127) << 20);
        k = (unsigned)(d4.z >> 7); slot = atomicAdd(&run[k], 1u);
        if (slot < CAP) part[(size_t)k * CAP + slot] = (unsigned)s4.z | ((unsigned)(d4.z & 127) << 20);
        k = (unsigned)(d4.w >> 7); slot = atomicAdd(&run[k], 1u);
        if (slot < CAP) part[(size_t)k * CAP + slot] = (unsigned)s4.w | ((unsigned)(d4.w & 127) << 20);
    }
}

// P4G: fused CSR-build + GEMM. One block per 128-node bucket — p4 and gemm1
// had IDENTICAL grids, and gemm's epilogue consumes dinv of exactly this
// bucket. Phase order: (a) stage Wt into LDS (global latency hides under p4),
// (b) p4: count/scan/emit rp,re,dinv + regroup col (scratch aliased into xs),
// (c) gemm: h'[rows of bucket] = dinv * (x@W1) with dinv read from LDS.
// LDS: wt 34816 + xs 18432 + dinvs 512 = 53760 B -> 3 blocks/CU (161.3KB/CU).
// Verified MFMA layouts: A[m=lane&15][k=(lane>>4)*8+j], B[k][n=lane&15],
//                        C/D col=lane&15 row=(lane>>4)*4+reg.
__launch_bounds__(256)
__global__ void p4g_k(const unsigned* __restrict__ part, const unsigned* __restrict__ gcnt,
                      const float* __restrict__ x, const _Float16* __restrict__ Wt,
                      unsigned* __restrict__ rp, unsigned* __restrict__ re,
                      float* __restrict__ dinv, unsigned* __restrict__ col,
                      _Float16* __restrict__ h) {
    __shared__ __align__(16) _Float16 wt[128 * 136];  // B: wt[n][k]; reused as epilogue buffer
    __shared__ __align__(16) _Float16 xs[128 * 72];   // A: xs[row][k]; p4 scratch aliased here
    __shared__ float dinvs[128];
    unsigned* cc  = (unsigned*)xs;   // [128] per-node counts   } alias, dead
    unsigned* pp  = cc + 128;        // [128] inclusive scan    } before xs
    unsigned* run = pp + 128;        // [128] running cursors   } staging
    int tid = threadIdx.x, k = blockIdx.x;
    int n0 = k << 7;
    int nodes = (NN - n0 < 128) ? (NN - n0) : 128;
    int w = tid >> 6, lane = tid & 63;
    int m = lane & 15, q4 = lane >> 4;

    // (a) stage Wt: 2048 half8 chunks, coalesced global, conflict-free LDS
#pragma unroll
    for (int q = 0; q < 8; q++) {
        int idx = q * 256 + tid;
        int n = idx >> 4, k8 = (idx & 15) * 8;
        *(half8*)(&wt[n * 136 + k8]) = *(const half8*)(Wt + n * 128 + k8);
    }

    // (b) p4 phase: bucket range is [k*CAP, k*CAP+cnt), no global scan needed
    unsigned cnt = gcnt[k * 16];
    if (cnt > CAP) cnt = CAP;  // overflow clamp (statistically impossible)
    unsigned e0c = (unsigned)k * CAP;
    const unsigned* pk = part + (size_t)k * CAP;

    if (tid < 128) cc[tid] = 0u;
    __syncthreads();
    for (unsigned t = tid; t < cnt; t += 256)
        atomicAdd(&cc[(pk[t] >> 20) & 127], 1u);
    __syncthreads();

    unsigned myc = (tid < 128) ? cc[tid] : 0u;
    if (tid < 128) pp[tid] = myc;
    __syncthreads();
    for (int off = 1; off < 128; off <<= 1) {
        unsigned u = 0;
        if (tid < 128 && tid >= off) u = pp[tid - off];
        __syncthreads();
        if (tid < 128) pp[tid] += u;
        __syncthreads();
    }
    if (tid < 128) {
        unsigned excl = pp[tid] - myc;
        run[tid] = excl;
        float dv = rsqrtf((float)(myc + 1u));
        dinvs[tid] = dv;
        if (tid < nodes) {
            rp[n0 + tid] = e0c + excl;
            re[n0 + tid] = e0c + excl + myc;
            dinv[n0 + tid] = dv;
        }
    }
    __syncthreads();

    for (unsigned t = tid; t < cnt; t += 256) {
        unsigned v = pk[t];
        unsigned dlo = (v >> 20) & 127;
        unsigned pos = e0c + atomicAdd(&run[dlo], 1u);
        col[pos] = v & 0xFFFFFu;
    }
    __syncthreads();  // run (aliased in xs) fully consumed before xs staging

    // (c) gemm phase: 4 waves; wave w covers rows w*32..w*32+31 (2 row-tiles)
    // x 8 col-tiles; x staged in K-halves of 64.
    f32x4 acc[2][8];
#pragma unroll
    for (int rt = 0; rt < 2; rt++)
#pragma unroll
        for (int nt = 0; nt < 8; nt++) acc[rt][nt] = (f32x4){0.f, 0.f, 0.f, 0.f};

    for (int ks = 0; ks <= 64; ks += 64) {
        if (ks) __syncthreads();  // previous xs fully consumed
        // stage x rows [n0, n0+128) cols [ks, ks+64), fp32 -> fp16
#pragma unroll
        for (int q = 0; q < 8; q++) {
            int idx = q * 256 + tid;        // 0..2047
            int row = idx >> 4;
            int c4 = (idx & 15) * 4;
            int gr = n0 + row;
            float4 v = (gr < NN) ? *(const float4*)(x + (size_t)gr * 128 + ks + c4)
                                 : make_float4(0, 0, 0, 0);
            half4v hv = { (_Float16)v.x, (_Float16)v.y, (_Float16)v.z, (_Float16)v.w };
            *(half4v*)(&xs[row * 72 + c4]) = hv;
        }
        __syncthreads();

#pragma unroll
        for (int kc = 0; kc < 2; kc++) {
            half8 a0 = *(const half8*)(&xs[(w * 32 + m) * 72 + kc * 32 + q4 * 8]);
            half8 a1 = *(const half8*)(&xs[(w * 32 + 16 + m) * 72 + kc * 32 + q4 * 8]);
#pragma unroll
            for (int nt = 0; nt < 8; nt++) {
                half8 bf = *(const half8*)(&wt[(nt * 16 + m) * 136 + ks + kc * 32 + q4 * 8]);
                acc[0][nt] = __builtin_amdgcn_mfma_f32_16x16x32_f16(a0, bf, acc[0][nt], 0, 0, 0);
                acc[1][nt] = __builtin_amdgcn_mfma_f32_16x16x32_f16(a1, bf, acc[1][nt], 0, 0, 0);
            }
        }
    }

    // epilogue: scale by dinv (from LDS), fp16, stage in wt (dead), coalesced store
    float dv[2][4];
#pragma unroll
    for (int rt = 0; rt < 2; rt++)
#pragma unroll
        for (int r = 0; r < 4; r++)
            dv[rt][r] = dinvs[w * 32 + rt * 16 + q4 * 4 + r];
    __syncthreads();  // all wt reads done
#pragma unroll
    for (int rt = 0; rt < 2; rt++)
#pragma unroll
        for (int nt = 0; nt < 8; nt++)
#pragma unroll
            for (int r = 0; r < 4; r++)
                wt[(w * 32 + rt * 16 + q4 * 4 + r) * 136 + nt * 16 + m] =
                    (_Float16)(acc[rt][nt][r] * dv[rt][r]);
    __syncthreads();
#pragma unroll
    for (int q = 0; q < 8; q++) {
        int idx = q * 256 + tid;
        int row = idx >> 4;
        int c8 = (idx & 15) * 8;
        int gr = n0 + row;
        if (gr < NN)
            *(half8*)(h + (size_t)gr * 128 + c8) = *(const half8*)(&wt[row * 136 + c8]);
    }
}

// Layer-1 aggregation of prescaled h' + bias/ReLU + 128x2 W2 projection.
// One wave per node; lane holds half2 (4B chunk; 64 lanes = full 256B row).
// Measured at the fill-path roofline (58.9 us vs 193MB/3.37TB/s = 57 us):
// col window loaded once (col[p0+lane]), row ids via readlane -> SGPR gather
// addresses, no degree tails: full 16-gather rounds, padding slots gather
// row i (hot), corrected exactly by f = 1 + deg - 16*ceil(deg/16).
__launch_bounds__(256)
__global__ void agg1_k(const _Float16* __restrict__ h, const unsigned* __restrict__ rp,
                       const unsigned* __restrict__ re, const unsigned* __restrict__ col,
                       const float* __restrict__ dinv, const float* __restrict__ b1,
                       const float* __restrict__ W2, float* __restrict__ z) {
    int i = (blockIdx.x * 256 + threadIdx.x) >> 6;
    int lane = threadIdx.x & 63;
    if (i >= NN) return;
    unsigned si = __builtin_amdgcn_readfirstlane((unsigned)i);  // force SGPR

    const __half2* hb = (const __half2*)h;
    unsigned p0 = __builtin_amdgcn_readfirstlane(rp[si]);
    unsigned p1 = __builtin_amdgcn_readfirstlane(re[si]);
    int deg = (int)(p1 - p0);

    // col window: one per-lane load covers up to 64 edge ids. May read past p1
    // (stays inside the padded slotted col); unused lanes masked by (k<degc).
    unsigned cv = col[p0 + (unsigned)lane];

    int degc = deg > 64 ? 64 : deg;
    int R = (degc + 15) >> 4;                 // full 16-rounds incl. padding
    float2 sv = __half22float2(hb[(size_t)si * 64u + lane]);
    float f = (float)(1 + degc - 16 * R);     // corrects padding reads of row si
    float ax = f * sv.x, ay = f * sv.y;

#define ROUND16(r)                                                           \
    {                                                                        \
        float2 vv[16];                                                       \
        _Pragma("unroll")                                                    \
        for (int t = 0; t < 16; t++) {                                       \
            int k = (r) * 16 + t;                                            \
            unsigned s = (k < degc) ? __builtin_amdgcn_readlane(cv, k) : si; \
            vv[t] = __half22float2(hb[(size_t)s * 64u + lane]);              \
        }                                                                    \
        ax += ((vv[0].x + vv[1].x) + (vv[2].x + vv[3].x))                    \
            + ((vv[4].x + vv[5].x) + (vv[6].x + vv[7].x))                    \
            + ((vv[8].x + vv[9].x) + (vv[10].x + vv[11].x))                  \
            + ((vv[12].x + vv[13].x) + (vv[14].x + vv[15].x));               \
        ay += ((vv[0].y + vv[1].y) + (vv[2].y + vv[3].y))                    \
            + ((vv[4].y + vv[5].y) + (vv[6].y + vv[7].y))                    \
            + ((vv[8].y + vv[9].y) + (vv[10].y + vv[11].y))                  \
            + ((vv[12].y + vv[13].y) + (vv[14].y + vv[15].y));               \
    }

    if (degc > 0)  ROUND16(0)
    if (degc > 16) ROUND16(1)
    if (degc > 32) ROUND16(2)
    if (degc > 48) ROUND16(3)
#undef ROUND16

    // deg > 64 remainder (Poisson(16): essentially never taken)
    for (unsigned e = p0 + 64; e < p1; ++e) {
        unsigned s_ = __builtin_amdgcn_readfirstlane(col[e]);
        float2 v = __half22float2(hb[(size_t)s_ * 64u + lane]);
        ax += v.x;
        ay += v.y;
    }

    float di = dinv[si];
    ax *= di;
    ay *= di;

    float2 bv = ((const float2*)b1)[lane];
    float h0 = fmaxf(ax + bv.x, 0.f);
    float h1 = fmaxf(ay + bv.y, 0.f);

    float4 w = ((const float4*)W2)[lane];
    float pz0 = fmaf(h0, w.x, h1 * w.z);
    float pz1 = fmaf(h0, w.y, h1 * w.w);
#pragma unroll
    for (int off = 32; off > 0; off >>= 1) {
        pz0 += __shfl_down(pz0, off);
        pz1 += __shfl_down(pz1, off);
    }
    if (lane == 0) {
        float2* zp = (float2*)(z + (size_t)si * 2);
        *zp = make_float2(pz0 * di, pz1 * di);  // prescale for layer-2 aggregation
    }
}

// Layer-2 aggregation over prescaled z'. 16 lanes per node (avg degree 16):
// 4 nodes/wave, width-16 shuffle reduce. out[i] = (Σ z'[s] + z'[i])*dinv[i] + b2.
__launch_bounds__(256)
__global__ void agg2_k(const float* __restrict__ z, const unsigned* __restrict__ rp,
                       const unsigned* __restrict__ re, const unsigned* __restrict__ col,
                       const float* __restrict__ dinv, const float* __restrict__ b2,
                       float* __restrict__ out) {
    int i = (blockIdx.x * 256 + threadIdx.x) >> 4;
    int sl = threadIdx.x & 15;
    if (i >= NN) return;

    unsigned p0 = rp[i], p1 = re[i];
    float a0 = 0.f, a1 = 0.f;
    for (unsigned e = p0 + sl; e < p1; e += 16) {
        unsigned s = col[e];
        float2 v = ((const float2*)z)[s];
        a0 += v.x;
        a1 += v.y;
    }
#pragma unroll
    for (int off = 8; off > 0; off >>= 1) {
        a0 += __shfl_down(a0, off, 16);
        a1 += __shfl_down(a1, off, 16);
    }
    if (sl == 0) {
        float di = dinv[i];
        float2 zi = ((const float2*)z)[i];
        out[(size_t)i * 2]     = (a0 + zi.x) * di + b2[0];
        out[(size_t)i * 2 + 1] = (a1 + zi.y) * di + b2[1];
    }
}

extern "C" void kernel_launch(void* const* d_in, const int* in_sizes, int n_in,
                              void* d_out, int out_size, void* d_ws, size_t ws_size,
                              hipStream_t stream) {
    const float* x  = (const float*)d_in[0];
    const int*   ei = (const int*)d_in[1];
    const float* W1 = (const float*)d_in[2];
    const float* b1 = (const float*)d_in[3];
    const float* W2 = (const float*)d_in[4];
    const float* b2 = (const float*)d_in[5];
    float* out = (float*)d_out;

    char* ws = (char*)d_ws;
    unsigned* part = (unsigned*)(ws);               // slotted buckets
    unsigned* gcnt = (unsigned*)(ws + 9609216);     // padded counters (1/line)
    float*    z    = (float*)(ws + 25600000);
    float*    dinv = (float*)(ws + 26400000);
    unsigned* rp   = (unsigned*)(ws + 26800000);
    unsigned* re   = (unsigned*)(ws + 27200000);
    unsigned* col  = (unsigned*)(ws + 27600000);
    _Float16* Wt   = (_Float16*)(ws + 37300000);
    _Float16* h    = (_Float16*)(ws + 40000000);    // own region (no part overlap!)

    hipMemsetAsync(gcnt, 0, 782 * 16 * sizeof(unsigned), stream);
    pscat_k<<<NBLK_P, 256, 0, stream>>>(ei, gcnt, part, W1, Wt);
    p4g_k<<<NBK, 256, 0, stream>>>(part, gcnt, x, Wt, rp, re, dinv, col, h);
    agg1_k<<<(NN * 64 + 255) / 256, 256, 0, stream>>>(h, rp, re, col, dinv, b1, W2, z);
    agg2_k<<<(NN * 16 + 255) / 256, 256, 0, stream>>>(z, rp, re, col, dinv, b2, out);
}